// Round 8
// baseline (125.995 us; speedup 1.0000x reference)
//
#include <hip/hip_runtime.h>
#include <math.h>

#define IC_   2048
#define NC_   16
#define OD_   16
#define ID_   8
#define B_    128
#define LOG2E_ 1.4426950408889634f

// pass1 geometry
#define P1_BB   8
#define P1_CH   64
#define P1_ICPB (IC_/P1_CH)     // 32 i per block
// pass2/3 geometry
#define P2_NCH  16              // pair-chunks per b: each block does 64 pairs (128 i)

typedef _Float16 h2 __attribute__((ext_vector_type(2)));
typedef _Float16 h8 __attribute__((ext_vector_type(8)));

// lane (l,k) -> original co: c = l&15, o = (l>>4)+4k
__device__ __forceinline__ int origco(int lane, int k) {
  return ((lane & 15) << 4) + (lane >> 4) + 4 * k;
}

template<int CTRL>
__device__ __forceinline__ float dpp_add(float x) {
  const int xi = __builtin_bit_cast(int, x);
  const int yi = __builtin_amdgcn_update_dpp(xi, xi, CTRL, 0xF, 0xF, false);
  return x + __builtin_bit_cast(float, yi);
}
// butterfly sum across each 16-lane row (result in all lanes of the row)
__device__ __forceinline__ float row16_sum(float x) {
  x = dpp_add<0x0B1>(x);  // quad_perm xor1
  x = dpp_add<0x04E>(x);  // quad_perm xor2
  x = dpp_add<0x141>(x);  // row_half_mirror xor4
  x = dpp_add<0x140>(x);  // row_mirror xor8
  return x;
}

__device__ __forceinline__ float dot8h(h8 w, h8 x) {
  const h2 w0 = __builtin_shufflevector(w, w, 0, 1), x0 = __builtin_shufflevector(x, x, 0, 1);
  const h2 w1 = __builtin_shufflevector(w, w, 2, 3), x1 = __builtin_shufflevector(x, x, 2, 3);
  const h2 w2 = __builtin_shufflevector(w, w, 4, 5), x2 = __builtin_shufflevector(x, x, 4, 5);
  const h2 w3 = __builtin_shufflevector(w, w, 6, 7), x3 = __builtin_shufflevector(x, x, 6, 7);
  float s = __builtin_amdgcn_fdot2(w0, x0, 0.f, false);
  s = __builtin_amdgcn_fdot2(w1, x1, s, false);
  s = __builtin_amdgcn_fdot2(w2, x2, s, false);
  s = __builtin_amdgcn_fdot2(w3, x3, s, false);
  return s;
}

__device__ __forceinline__ unsigned int packh2(float a, float b) {
  h2 h; h[0] = (_Float16)a; h[1] = (_Float16)b;
  return __builtin_bit_cast(unsigned int, h);
}

// ---------- fused conversion: W fp32->fp16 with row permutation, x fp32->fp16 ----------
// Wp[i][rp] = W[i][ro], ro = c*16+o -> rp = c + ((o&3)<<4) + ((o>>2)<<6).
// Blocks [0,2048): W. Blocks [2048,3072): x (one h8-group per thread).
__global__ __launch_bounds__(256)
void cvtWX(const float* __restrict__ W, const float* __restrict__ x,
           _Float16* __restrict__ Wh, _Float16* __restrict__ xh) {
  if (blockIdx.x < 2048) {
    const int idx = blockIdx.x * 256 + threadIdx.x;   // i*256 + ro
    const int ro  = idx & 255;
    const int i   = idx >> 8;
    const int rp  = (ro >> 4) + ((ro & 3) << 4) + (((ro >> 2) & 3) << 6);
    const float4 a = ((const float4*)W)[2 * idx];
    const float4 b = ((const float4*)W)[2 * idx + 1];
    h8 h;
    h[0] = (_Float16)a.x; h[1] = (_Float16)a.y; h[2] = (_Float16)a.z; h[3] = (_Float16)a.w;
    h[4] = (_Float16)b.x; h[5] = (_Float16)b.y; h[6] = (_Float16)b.z; h[7] = (_Float16)b.w;
    *(h8*)(Wh + ((size_t)i * 256 + rp) * ID_) = h;
  } else {
    const int idx = (blockIdx.x - 2048) * 256 + threadIdx.x;   // h8-group of x
    const float4 a = ((const float4*)x)[2 * idx];
    const float4 b = ((const float4*)x)[2 * idx + 1];
    h8 h;
    h[0] = (_Float16)a.x; h[1] = (_Float16)a.y; h[2] = (_Float16)a.z; h[3] = (_Float16)a.w;
    h[4] = (_Float16)b.x; h[5] = (_Float16)b.y; h[6] = (_Float16)b.z; h[7] = (_Float16)b.w;
    ((h8*)xh)[idx] = h;
  }
}

// ---------- pass 1: u_hat (fp16, pair-interleaved) + uniform-weight s1 partials ----------
// Grid (16 bg, 64 ch). Wave handles i-PAIRS: ip = ch*32 + t*8 + wid*2, t<4.
// u_hat dword layout: [(b*1024 + ip/2)*256 + lane*4] = {i0:(u0,u1),(u2,u3), i1:(u0,u1),(u2,u3)}
// where uk = u[b, i, origco(lane,k)].
__global__ __launch_bounds__(256)
void caps_pass1(const _Float16* __restrict__ xh, const _Float16* __restrict__ Wp,
                unsigned int* __restrict__ u_hat, float* __restrict__ s_part) {
  const int bg = blockIdx.x;
  const int ch = blockIdx.y;
  const int tid = threadIdx.x, wid = tid >> 6, lane = tid & 63;

  float acc[P1_BB][4];
#pragma unroll
  for (int bb = 0; bb < P1_BB; ++bb)
#pragma unroll
    for (int k = 0; k < 4; ++k) acc[bb][k] = 0.f;

  for (int t = 0; t < 4; ++t) {
    const int ip = ch * P1_ICPB + t * 8 + wid * 2;
    const _Float16* wr0 = Wp + (size_t)ip * 2048 + lane * ID_;
    const _Float16* wr1 = wr0 + 2048;
    const h8 wA0 = *(const h8*)(wr0);
    const h8 wA1 = *(const h8*)(wr0 + 512);
    const h8 wA2 = *(const h8*)(wr0 + 1024);
    const h8 wA3 = *(const h8*)(wr0 + 1536);
    const h8 wB0 = *(const h8*)(wr1);
    const h8 wB1 = *(const h8*)(wr1 + 512);
    const h8 wB2 = *(const h8*)(wr1 + 1024);
    const h8 wB3 = *(const h8*)(wr1 + 1536);

#pragma unroll
    for (int bb = 0; bb < P1_BB; ++bb) {
      const int b = bg * P1_BB + bb;
      const _Float16* xp = xh + ((size_t)b * IC_ + ip) * ID_;
      const h8 xv0 = *(const h8*)(xp);
      const h8 xv1 = *(const h8*)(xp + ID_);

      const float u00 = dot8h(wA0, xv0);
      const float u01 = dot8h(wA1, xv0);
      const float u02 = dot8h(wA2, xv0);
      const float u03 = dot8h(wA3, xv0);
      const float u10 = dot8h(wB0, xv1);
      const float u11 = dot8h(wB1, xv1);
      const float u12 = dot8h(wB2, xv1);
      const float u13 = dot8h(wB3, xv1);

      acc[bb][0] += u00 + u10;
      acc[bb][1] += u01 + u11;
      acc[bb][2] += u02 + u12;
      acc[bb][3] += u03 + u13;

      uint4 q;
      q.x = packh2(u00, u01);
      q.y = packh2(u02, u03);
      q.z = packh2(u10, u11);
      q.w = packh2(u12, u13);
      *(uint4*)(u_hat + ((size_t)b * 1024 + (ip >> 1)) * 256 + lane * 4) = q;
    }
  }

  // conflict-free padded reduce: slot(o,c) = o*17 + c
  __shared__ float red[4][P1_BB][272];
#pragma unroll
  for (int bb = 0; bb < P1_BB; ++bb)
#pragma unroll
    for (int k = 0; k < 4; ++k)
      red[wid][bb][((lane >> 4) + 4 * k) * 17 + (lane & 15)] = acc[bb][k];
  __syncthreads();
#pragma unroll
  for (int bb = 0; bb < P1_BB; ++bb) {
    const int addr = (tid & 15) * 17 + (tid >> 4);   // tid = co = c*16+o
    const float s = red[0][bb][addr] + red[1][bb][addr] + red[2][bb][addr] + red[3][bb][addr];
    s_part[((size_t)(bg * P1_BB + bb) * P1_CH + ch) * 256 + tid] = s;
  }
}

// ---------- pass 2/3: streaming softmax-weighted accumulation over u_hat ----------
// Grid (B, 16). Block = 4 waves, same b; wave handles 16 pairs (32 i), dwordx4 per pair.
__global__ __launch_bounds__(256)
void caps_wpass(const unsigned int* __restrict__ u_hat, const float* __restrict__ vs,
                float* __restrict__ s_part) {
  const int b   = blockIdx.x;
  const int ich = blockIdx.y;
  const int tid = threadIdx.x, wid = tid >> 6, lane = tid & 63;

  const float vv0 = vs[b * 256 + origco(lane, 0)];
  const float vv1 = vs[b * 256 + origco(lane, 1)];
  const float vv2 = vs[b * 256 + origco(lane, 2)];
  const float vv3 = vs[b * 256 + origco(lane, 3)];

  float a0 = 0.f, a1 = 0.f, a2 = 0.f, a3 = 0.f;
  const unsigned int* up =
      u_hat + ((size_t)b * 1024 + ich * 64 + wid * 16) * 256 + lane * 4;

#pragma unroll 4
  for (int t = 0; t < 16; ++t) {
    const uint4 q = *(const uint4*)(up + (size_t)t * 256);

    // i0
    {
      const h2 ha = __builtin_bit_cast(h2, q.x);
      const h2 hb = __builtin_bit_cast(h2, q.y);
      const float u0 = (float)ha[0], u1 = (float)ha[1];
      const float u2 = (float)hb[0], u3 = (float)hb[1];
      float p = u0 * vv0;
      p = fmaf(u1, vv1, p);
      p = fmaf(u2, vv2, p);
      p = fmaf(u3, vv3, p);
      p += __shfl_xor(p, 16);
      p += __shfl_xor(p, 32);
      const float e = __builtin_amdgcn_exp2f(p);
      const float Z = row16_sum(e);
      const float w = e * __builtin_amdgcn_rcpf(Z);
      a0 = fmaf(w, u0, a0);
      a1 = fmaf(w, u1, a1);
      a2 = fmaf(w, u2, a2);
      a3 = fmaf(w, u3, a3);
    }
    // i1
    {
      const h2 ha = __builtin_bit_cast(h2, q.z);
      const h2 hb = __builtin_bit_cast(h2, q.w);
      const float u0 = (float)ha[0], u1 = (float)ha[1];
      const float u2 = (float)hb[0], u3 = (float)hb[1];
      float p = u0 * vv0;
      p = fmaf(u1, vv1, p);
      p = fmaf(u2, vv2, p);
      p = fmaf(u3, vv3, p);
      p += __shfl_xor(p, 16);
      p += __shfl_xor(p, 32);
      const float e = __builtin_amdgcn_exp2f(p);
      const float Z = row16_sum(e);
      const float w = e * __builtin_amdgcn_rcpf(Z);
      a0 = fmaf(w, u0, a0);
      a1 = fmaf(w, u1, a1);
      a2 = fmaf(w, u2, a2);
      a3 = fmaf(w, u3, a3);
    }
  }

  __shared__ float red[4][272];
  red[wid][((lane >> 4) + 0) * 17 + (lane & 15)]  = a0;
  red[wid][((lane >> 4) + 4) * 17 + (lane & 15)]  = a1;
  red[wid][((lane >> 4) + 8) * 17 + (lane & 15)]  = a2;
  red[wid][((lane >> 4) + 12) * 17 + (lane & 15)] = a3;
  __syncthreads();
  const int addr = (tid & 15) * 17 + (tid >> 4);
  const float s = red[0][addr] + red[1][addr] + red[2][addr] + red[3][addr];
  s_part[((size_t)b * P2_NCH + ich) * 256 + tid] = s;
}

// ---------- reduce over nch chunks + squash ----------
// mode 0: vraw=v1, vs_next=v1*log2e (scale=1/16); mode 1: vs_next=(v1raw+v2)*log2e;
// mode 2: out=v3.
__global__ __launch_bounds__(256)
void caps_reduce(const float* __restrict__ s_part, float* __restrict__ vraw,
                 float* __restrict__ vs_next, float* __restrict__ out,
                 const float* __restrict__ v_prev_raw, float scale, int mode, int nch) {
  const int b = blockIdx.x, t = threadIdx.x;
  float s = 0.f;
  for (int ch = 0; ch < nch; ++ch)
    s += s_part[((size_t)b * nch + ch) * 256 + t];
  s *= scale;
  float sq = s * s;
  sq += __shfl_xor(sq, 1); sq += __shfl_xor(sq, 2);
  sq += __shfl_xor(sq, 4); sq += __shfl_xor(sq, 8);
  const float f = sq / ((1.f + sq) * sqrtf(sq + 1e-8f));
  const float v = s * f;
  if (mode == 0) { vraw[b*256+t] = v; vs_next[b*256+t] = v * LOG2E_; }
  else if (mode == 1) { vs_next[b*256+t] = (v + v_prev_raw[b*256+t]) * LOG2E_; }
  else { out[b*256+t] = v; }
}

// ================= fp32 fallback (round-3 proven) =================
__device__ __forceinline__ float4 ld4(const float* p) { return *(const float4*)p; }
__device__ __forceinline__ float dot8f(float4 a0, float4 a1, float4 b0, float4 b1) {
  float s = a0.x * b0.x;
  s = fmaf(a0.y, b0.y, s); s = fmaf(a0.z, b0.z, s); s = fmaf(a0.w, b0.w, s);
  s = fmaf(a1.x, b1.x, s); s = fmaf(a1.y, b1.y, s); s = fmaf(a1.z, b1.z, s);
  s = fmaf(a1.w, b1.w, s);
  return s;
}
template<bool UNIFORM, int CH>
__global__ __launch_bounds__(256)
void caps_pass_f32(const float* __restrict__ x, const float* __restrict__ W,
                   const float* __restrict__ vs, float* __restrict__ s_part) {
  constexpr int ICPB  = IC_ / CH;
  constexpr int TITER = ICPB / 4;
  const int bg = blockIdx.x, ch = blockIdx.y, tid = threadIdx.x;
  const int wid = tid >> 6, lane = tid & 63;
  float4 vr[4];
  if (!UNIFORM) {
#pragma unroll
    for (int bb = 0; bb < 4; ++bb) {
      const float* vp = vs + (size_t)(bg * 4 + bb) * 256 + lane;
      vr[bb] = make_float4(vp[0], vp[64], vp[128], vp[192]);
    }
  }
  float4 acc[4];
#pragma unroll
  for (int bb = 0; bb < 4; ++bb) acc[bb] = make_float4(0.f, 0.f, 0.f, 0.f);
  for (int t = 0; t < TITER; ++t) {
    const int i = ch * ICPB + t * 4 + wid;
    const float* wr = W + (size_t)i * 2048 + lane * 8;
    const float4 wa0 = ld4(wr);        const float4 wa1 = ld4(wr + 4);
    const float4 wb0 = ld4(wr + 512);  const float4 wb1 = ld4(wr + 516);
    const float4 wc0 = ld4(wr + 1024); const float4 wc1 = ld4(wr + 1028);
    const float4 wd0 = ld4(wr + 1536); const float4 wd1 = ld4(wr + 1540);
#pragma unroll
    for (int bb = 0; bb < 4; ++bb) {
      const float* xp = x + ((size_t)(bg * 4 + bb) * IC_ + i) * ID_;
      const float4 x0 = ld4(xp), x1 = ld4(xp + 4);
      const float u0 = dot8f(wa0, wa1, x0, x1);
      const float u1 = dot8f(wb0, wb1, x0, x1);
      const float u2 = dot8f(wc0, wc1, x0, x1);
      const float u3 = dot8f(wd0, wd1, x0, x1);
      if (UNIFORM) {
        acc[bb].x += u0; acc[bb].y += u1; acc[bb].z += u2; acc[bb].w += u3;
      } else {
        const float d0 = row16_sum(u0 * vr[bb].x);
        const float d1 = row16_sum(u1 * vr[bb].y);
        const float d2 = row16_sum(u2 * vr[bb].z);
        const float d3 = row16_sum(u3 * vr[bb].w);
        const float e0 = __builtin_amdgcn_exp2f(d0);
        const float e1 = __builtin_amdgcn_exp2f(d1);
        const float e2 = __builtin_amdgcn_exp2f(d2);
        const float e3 = __builtin_amdgcn_exp2f(d3);
        float Z = (e0 + e1) + (e2 + e3);
        Z += __shfl_xor(Z, 16); Z += __shfl_xor(Z, 32);
        const float rr = __builtin_amdgcn_rcpf(Z);
        acc[bb].x = fmaf(e0 * rr, u0, acc[bb].x);
        acc[bb].y = fmaf(e1 * rr, u1, acc[bb].y);
        acc[bb].z = fmaf(e2 * rr, u2, acc[bb].z);
        acc[bb].w = fmaf(e3 * rr, u3, acc[bb].w);
      }
    }
  }
  __shared__ float red[4][4 * 256];
#pragma unroll
  for (int bb = 0; bb < 4; ++bb) {
    red[wid][bb * 256 + lane]       = acc[bb].x;
    red[wid][bb * 256 + lane + 64]  = acc[bb].y;
    red[wid][bb * 256 + lane + 128] = acc[bb].z;
    red[wid][bb * 256 + lane + 192] = acc[bb].w;
  }
  __syncthreads();
#pragma unroll
  for (int bb = 0; bb < 4; ++bb) {
    const int idx = bb * 256 + tid;
    const float s = red[0][idx] + red[1][idx] + red[2][idx] + red[3][idx];
    s_part[((size_t)(bg * 4 + bb) * CH + ch) * 256 + tid] = s;
  }
}

extern "C" void kernel_launch(void* const* d_in, const int* in_sizes, int n_in,
                              void* d_out, int out_size, void* d_ws, size_t ws_size,
                              hipStream_t stream) {
  (void)in_sizes; (void)n_in; (void)out_size;

  const float* x = (const float*)d_in[0];
  const float* W = (const float*)d_in[1];
  float* out = (float*)d_out;

  const size_t u_dw  = (size_t)B_ * 1024 * 256;           // 32 Mi dwords = 128 MiB
  const size_t sp_f  = (size_t)B_ * P1_CH * 256;          // 8 MiB of f32
  const size_t v_f   = (size_t)B_ * 256;
  const size_t nW    = (size_t)IC_ * 256 * ID_;           // 4 Mi fp16
  const size_t nX    = (size_t)B_ * IC_ * ID_;            // 2 Mi fp16
  const size_t need  = u_dw * 4 + sp_f * 4 + 2 * v_f * 4 + (nW + nX) * 2;  // ~148 MiB

  const dim3 blk(256), gridR(B_);

  if (ws_size >= need) {
    unsigned int* u_hat = (unsigned int*)d_ws;
    float* s_part = (float*)(u_hat + u_dw);
    float* v1raw  = s_part + sp_f;
    float* vsb    = v1raw + v_f;
    _Float16* Wh  = (_Float16*)(vsb + v_f);
    _Float16* xh  = Wh + nW;

    cvtWX<<<3072, blk, 0, stream>>>(W, x, Wh, xh);

    caps_pass1<<<dim3(B_ / P1_BB, P1_CH), blk, 0, stream>>>(xh, Wh, u_hat, s_part);
    caps_reduce<<<gridR, blk, 0, stream>>>(s_part, v1raw, vsb, nullptr, nullptr,
                                           1.f / 16.f, 0, P1_CH);
    caps_wpass<<<dim3(B_, P2_NCH), blk, 0, stream>>>(u_hat, vsb, s_part);
    caps_reduce<<<gridR, blk, 0, stream>>>(s_part, nullptr, vsb, nullptr, v1raw,
                                           1.f, 1, P2_NCH);
    caps_wpass<<<dim3(B_, P2_NCH), blk, 0, stream>>>(u_hat, vsb, s_part);
    caps_reduce<<<gridR, blk, 0, stream>>>(s_part, nullptr, nullptr, out, nullptr,
                                           1.f, 2, P2_NCH);
  } else {
    constexpr int CH = 32;
    float* s_part = (float*)d_ws;
    float* v1raw  = s_part + (size_t)B_ * CH * 256;
    float* vsb    = v1raw + (size_t)B_ * 256;
    const dim3 gridP(B_ / 4, CH);
    caps_pass_f32<true , CH><<<gridP, blk, 0, stream>>>(x, W, nullptr, s_part);
    caps_reduce<<<gridR, blk, 0, stream>>>(s_part, v1raw, vsb, nullptr, nullptr, 1.f/16.f, 0, CH);
    caps_pass_f32<false, CH><<<gridP, blk, 0, stream>>>(x, W, vsb, s_part);
    caps_reduce<<<gridR, blk, 0, stream>>>(s_part, nullptr, vsb, nullptr, v1raw, 1.f, 1, CH);
    caps_pass_f32<false, CH><<<gridP, blk, 0, stream>>>(x, W, vsb, s_part);
    caps_reduce<<<gridR, blk, 0, stream>>>(s_part, nullptr, nullptr, out, nullptr, 1.f, 2, CH);
  }
}